// Round 2
// baseline (967.073 us; speedup 1.0000x reference)
//
#include <hip/hip_runtime.h>
#include <hip/hip_bf16.h>

// ---------------------------------------------------------------------------
// MiniTransformer: B=8,S=2048,D=1024,H=2048, fp32 in/out, bf16 MFMA inside.
// Pipeline (10 launches):
//   1-3. gemm_bt: q = x@Wq^T (bf16), k = x@Wk^T (bf16), vT = (x@Wv^T)^T (bf16, (B,D,S))
//   4.   gemm_bt: scores = q@k^T * 1/32  (bf16, per-batch)
//   5.   softmax rows (in-place on scores -> P)
//   6.   gemm_bt: res1 = P@V + x        (fp32, uses vT as B^T operand)
//   7.   LN1: h (fp32, lives in d_out) + hb (bf16, aliases qb)
//   8.   gemm_bt: ff1 = relu(hb@W1^T + b1) (bf16, reuses scores buffer)
//   9.   gemm_bt: res2 = ff1@W2^T + b2 + h (fp32, reuses r1 buffer)
//   10.  LN2: reads r1, writes d_out (overwrites h)
// Scratch map (d_ws), total 234,881,024 B (< 256 MiB):
//   qb   : bf16 BSD (q;   later reused as hb)
//   kb   : bf16 BSD
//   vTb  : bf16 BSD ((B,D,S) layout so PV is a B^T-pattern GEMM)
//   sP   : bf16 BSS (scores -> P -> ff1)
//   r1   : fp32 BSD (attn_out+x -> res2)
//   h lives in d_out (exactly BSD fp32); LN2 overwrites it at the end.
// ---------------------------------------------------------------------------

typedef __attribute__((ext_vector_type(4))) float  f32x4;
typedef __attribute__((ext_vector_type(8))) short  short8;
typedef __attribute__((ext_vector_type(4))) short  short4v;
typedef __attribute__((ext_vector_type(8))) __bf16 bf16x8;

static __device__ __forceinline__ unsigned short f2bf(float f) {
  unsigned u = __builtin_bit_cast(unsigned, f);
  u += 0x7fffu + ((u >> 16) & 1u);          // RNE
  return (unsigned short)(u >> 16);
}
static __device__ __forceinline__ float bf2f(unsigned short u) {
  return __builtin_bit_cast(float, (unsigned)u << 16);
}

// ---------------------------------------------------------------------------
// GEMM: C[M,N] = A[M,K] @ B[N,K]^T   (A,B row-major; B^T pattern everywhere)
// 128x128 tile, BK=64, 256 threads = 4 waves in 2x2, mfma_f32_16x16x32_bf16.
// LDS tiles [128][64] bf16 (128B rows) with byte ^= ((row&7)<<4) XOR swizzle.
// ---------------------------------------------------------------------------
constexpr int BM = 128, BN = 128, BK = 64;

enum { EP_BF16 = 0, EP_VT = 1, EP_PV = 2, EP_FF1 = 3, EP_FF2 = 4 };

template <typename T>
static __device__ __forceinline__ void stage_tile(unsigned short* dst,
                                                  const T* __restrict__ G,
                                                  long row0, int k0, int ldg,
                                                  int tid) {
  // 128 rows x 64 cols = 1024 chunks of 8 elements; 4 chunks/thread.
#pragma unroll
  for (int it = 0; it < 4; ++it) {
    int c   = tid + it * 256;
    int row = c >> 3;
    int cb  = (c & 7) << 4;  // byte offset of 16B chunk within 128B row
    const T* src = G + (row0 + row) * (long)ldg + k0 + ((c & 7) << 3);
    short8 t;
    if constexpr (sizeof(T) == 4) {
      const f32x4* f4 = (const f32x4*)src;
      f32x4 a = f4[0], b = f4[1];
      t[0] = (short)f2bf(a.x); t[1] = (short)f2bf(a.y);
      t[2] = (short)f2bf(a.z); t[3] = (short)f2bf(a.w);
      t[4] = (short)f2bf(b.x); t[5] = (short)f2bf(b.y);
      t[6] = (short)f2bf(b.z); t[7] = (short)f2bf(b.w);
    } else {
      t = *(const short8*)src;
    }
    int byte = (row << 7) + (cb ^ ((row & 7) << 4));
    *(short8*)((char*)dst + byte) = t;
  }
}

template <int EPI, typename TA, typename TB>
__global__ __launch_bounds__(256) void gemm_bt(
    const TA* __restrict__ A, const TB* __restrict__ B, void* __restrict__ C,
    int M, int N, int K, long sA, long sB, long sC, long sRes,
    const float* __restrict__ bias, const float* __restrict__ res,
    float scale) {
  __shared__ __align__(16) unsigned short As[BM * BK];
  __shared__ __align__(16) unsigned short Bs[BN * BK];
  const int tid  = threadIdx.x;
  const int lane = tid & 63;
  const int w    = tid >> 6;
  const int wr   = (w >> 1) * 64, wc = (w & 1) * 64;
  const long bz  = blockIdx.z;
  const long m0  = (long)blockIdx.x * BM;
  const long n0  = (long)blockIdx.y * BN;
  const TA* Ab   = A + bz * sA;
  const TB* Bb   = B + bz * sB;

  f32x4 acc[4][4] = {};

  for (int k0 = 0; k0 < K; k0 += BK) {
    __syncthreads();
    stage_tile<TA>(As, Ab, m0, k0, K, tid);
    stage_tile<TB>(Bs, Bb, n0, k0, K, tid);
    __syncthreads();
#pragma unroll
    for (int kk = 0; kk < BK / 32; ++kk) {
      short8 af[4], bf[4];
      const int cb = kk * 64 + ((lane >> 4) << 4);
#pragma unroll
      for (int i = 0; i < 4; ++i) {
        int ra = wr + i * 16 + (lane & 15);
        af[i]  = *(const short8*)((const char*)As + (ra << 7) +
                                 (cb ^ ((ra & 7) << 4)));
        int rb = wc + i * 16 + (lane & 15);
        bf[i]  = *(const short8*)((const char*)Bs + (rb << 7) +
                                 (cb ^ ((rb & 7) << 4)));
      }
#pragma unroll
      for (int i = 0; i < 4; ++i)
#pragma unroll
        for (int j = 0; j < 4; ++j)
          acc[i][j] = __builtin_amdgcn_mfma_f32_16x16x32_bf16(
              __builtin_bit_cast(bf16x8, af[i]),
              __builtin_bit_cast(bf16x8, bf[j]), acc[i][j], 0, 0, 0);
    }
  }

  // Epilogue. C/D layout (verified m89): col = lane&15, row = (lane>>4)*4+reg.
  const int rb0 = ((lane >> 4) << 2);
  const int cl  = (lane & 15);
#pragma unroll
  for (int i = 0; i < 4; ++i) {
#pragma unroll
    for (int j = 0; j < 4; ++j) {
      long gmb = m0 + wr + i * 16 + rb0;
      long gc  = n0 + wc + j * 16 + cl;
      if constexpr (EPI == EP_VT) {
        // vT is (B=8, D=1024, S=2048); gm encodes b = gm>>11, s = gm&2047.
        long bb = gmb >> 11;
        long s  = gmb & 2047;
        short4v pk;
#pragma unroll
        for (int r = 0; r < 4; ++r) pk[r] = (short)f2bf(acc[i][j][r]);
        *(short4v*)((unsigned short*)C + ((bb << 10) + gc) * 2048 + s) = pk;
      } else {
#pragma unroll
        for (int r = 0; r < 4; ++r) {
          long gm = gmb + r;
          float v = acc[i][j][r] * scale;
          if constexpr (EPI == EP_BF16) {
            ((unsigned short*)C)[bz * sC + gm * N + gc] = f2bf(v);
          } else if constexpr (EPI == EP_PV) {
            v += res[bz * sRes + gm * N + gc];
            ((float*)C)[bz * sC + gm * N + gc] = v;
          } else if constexpr (EPI == EP_FF1) {
            v += bias[gc];
            v = v > 0.f ? v : 0.f;
            ((unsigned short*)C)[gm * N + gc] = f2bf(v);
          } else {  // EP_FF2
            v += bias[gc] + res[gm * N + gc];
            ((float*)C)[gm * N + gc] = v;
          }
        }
      }
    }
  }
}

// ---------------------------------------------------------------------------
// Row softmax, in place on bf16 (B*S rows of 2048). 256 thr, 8 el/thread.
// ---------------------------------------------------------------------------
__global__ __launch_bounds__(256) void softmax_inplace(
    unsigned short* __restrict__ P) {
  __shared__ float rmax[4], rsum[4];
  const int tid   = threadIdx.x;
  const long base = (long)blockIdx.x * 2048;
  short8 sv = *(const short8*)(P + base + tid * 8);
  float v[8];
#pragma unroll
  for (int j = 0; j < 8; ++j) v[j] = bf2f((unsigned short)sv[j]);
  float mx = v[0];
#pragma unroll
  for (int j = 1; j < 8; ++j) mx = fmaxf(mx, v[j]);
#pragma unroll
  for (int off = 32; off; off >>= 1) mx = fmaxf(mx, __shfl_down(mx, off, 64));
  if ((tid & 63) == 0) rmax[tid >> 6] = mx;
  __syncthreads();
  mx = fmaxf(fmaxf(rmax[0], rmax[1]), fmaxf(rmax[2], rmax[3]));
  float s = 0.f;
#pragma unroll
  for (int j = 0; j < 8; ++j) {
    v[j] = __expf(v[j] - mx);
    s += v[j];
  }
#pragma unroll
  for (int off = 32; off; off >>= 1) s += __shfl_down(s, off, 64);
  if ((tid & 63) == 0) rsum[tid >> 6] = s;
  __syncthreads();
  s = (rsum[0] + rsum[1]) + (rsum[2] + rsum[3]);
  float inv = 1.f / s;
  short8 o;
#pragma unroll
  for (int j = 0; j < 8; ++j) o[j] = (short)f2bf(v[j] * inv);
  *(short8*)(P + base + tid * 8) = o;
}

// ---------------------------------------------------------------------------
// Row LayerNorm over D=1024. MODE 0: write fp32 + bf16; MODE 1: fp32 only.
// ---------------------------------------------------------------------------
template <int MODE>
__global__ __launch_bounds__(256) void ln_row(const float* __restrict__ X,
                                              const float* __restrict__ g,
                                              const float* __restrict__ be,
                                              float* __restrict__ Yf,
                                              unsigned short* __restrict__ Yb) {
  __shared__ float rs[4], rq[4];
  const int tid   = threadIdx.x;
  const long base = (long)blockIdx.x << 10;
  f32x4 v = *(const f32x4*)(X + base + tid * 4);
  float s = v.x + v.y + v.z + v.w;
  float q = v.x * v.x + v.y * v.y + v.z * v.z + v.w * v.w;
#pragma unroll
  for (int off = 32; off; off >>= 1) {
    s += __shfl_down(s, off, 64);
    q += __shfl_down(q, off, 64);
  }
  if ((tid & 63) == 0) {
    rs[tid >> 6] = s;
    rq[tid >> 6] = q;
  }
  __syncthreads();
  s = (rs[0] + rs[1]) + (rs[2] + rs[3]);
  q = (rq[0] + rq[1]) + (rq[2] + rq[3]);
  float mu   = s * (1.f / 1024.f);
  float var  = q * (1.f / 1024.f) - mu * mu;
  float rstd = rsqrtf(var + 1e-5f);
  int c    = tid * 4;
  f32x4 gg = *(const f32x4*)(g + c);
  f32x4 bb = *(const f32x4*)(be + c);
  f32x4 y;
  y.x = (v.x - mu) * rstd * gg.x + bb.x;
  y.y = (v.y - mu) * rstd * gg.y + bb.y;
  y.z = (v.z - mu) * rstd * gg.z + bb.z;
  y.w = (v.w - mu) * rstd * gg.w + bb.w;
  *(f32x4*)(Yf + base + c) = y;
  if constexpr (MODE == 0) {
    short4v ob;
    ob[0] = (short)f2bf(y.x);
    ob[1] = (short)f2bf(y.y);
    ob[2] = (short)f2bf(y.z);
    ob[3] = (short)f2bf(y.w);
    *(short4v*)(Yb + base + c) = ob;
  }
}

// ---------------------------------------------------------------------------
extern "C" void kernel_launch(void* const* d_in, const int* in_sizes, int n_in,
                              void* d_out, int out_size, void* d_ws,
                              size_t ws_size, hipStream_t stream) {
  const float* x   = (const float*)d_in[0];
  const float* Wq  = (const float*)d_in[1];
  const float* Wk  = (const float*)d_in[2];
  const float* Wv  = (const float*)d_in[3];
  const float* W1  = (const float*)d_in[4];
  const float* b1  = (const float*)d_in[5];
  const float* W2  = (const float*)d_in[6];
  const float* b2  = (const float*)d_in[7];
  const float* g1  = (const float*)d_in[8];
  const float* be1 = (const float*)d_in[9];
  const float* g2  = (const float*)d_in[10];
  const float* be2 = (const float*)d_in[11];
  float* out = (float*)d_out;

  constexpr long BSD = 8L * 2048 * 1024;  // 16,777,216
  constexpr long BSS = 8L * 2048 * 2048;  // 33,554,432

  // Scratch map: 3 bf16 BSD + 1 bf16 BSS + 1 fp32 BSD = 234,881,024 bytes.
  unsigned short* qb  = (unsigned short*)d_ws;  // q; reused as hb after step 4
  unsigned short* kb  = qb + BSD;
  unsigned short* vTb = kb + BSD;
  unsigned short* sP  = vTb + BSD;       // scores -> P -> ff1 (bf16, BSS)
  float* r1 = (float*)(sP + BSS);        // attn_out+x -> res2 (fp32, BSD)
  unsigned short* hb = qb;               // alias: qb dead after scores GEMM
  float* h = out;                        // alias: d_out dead until LN2 rewrite

  dim3 blk(256);
  const long SD = 2048L * 1024, SS = 2048L * 2048, DS = 1024L * 2048;

  // 1-3: QKV projections (M=16384, N=1024, K=1024)
  gemm_bt<EP_BF16, float, float><<<dim3(128, 8, 1), blk, 0, stream>>>(
      x, Wq, qb, 16384, 1024, 1024, 0, 0, 0, 0, nullptr, nullptr, 1.f);
  gemm_bt<EP_BF16, float, float><<<dim3(128, 8, 1), blk, 0, stream>>>(
      x, Wk, kb, 16384, 1024, 1024, 0, 0, 0, 0, nullptr, nullptr, 1.f);
  gemm_bt<EP_VT, float, float><<<dim3(128, 8, 1), blk, 0, stream>>>(
      x, Wv, vTb, 16384, 1024, 1024, 0, 0, 0, 0, nullptr, nullptr, 1.f);
  // 4: scores = q@k^T / 32 (per batch: M=N=2048, K=1024)
  gemm_bt<EP_BF16, unsigned short, unsigned short>
      <<<dim3(16, 16, 8), blk, 0, stream>>>(qb, kb, sP, 2048, 2048, 1024, SD,
                                            SD, SS, 0, nullptr, nullptr,
                                            0.03125f);
  // 5: softmax
  softmax_inplace<<<dim3(16384), blk, 0, stream>>>(sP);
  // 6: attn_out + x (per batch: M=2048, N=1024, K=2048)
  gemm_bt<EP_PV, unsigned short, unsigned short>
      <<<dim3(16, 8, 8), blk, 0, stream>>>(sP, vTb, r1, 2048, 1024, 2048, SS,
                                           DS, SD, SD, nullptr, x, 1.f);
  // 7: LN1 -> h (fp32, in d_out) + hb (bf16, aliases qb)
  ln_row<0><<<dim3(16384), blk, 0, stream>>>(r1, g1, be1, h, hb);
  // 8: ff1 = relu(h@W1^T + b1) (M=16384, N=2048, K=1024)
  gemm_bt<EP_FF1, unsigned short, float><<<dim3(128, 16, 1), blk, 0, stream>>>(
      hb, W1, sP, 16384, 2048, 1024, 0, 0, 0, 0, b1, nullptr, 1.f);
  // 9: res2 = ff1@W2^T + b2 + h (M=16384, N=1024, K=2048)
  gemm_bt<EP_FF2, unsigned short, float><<<dim3(128, 8, 1), blk, 0, stream>>>(
      sP, W2, r1, 16384, 1024, 2048, 0, 0, 0, 0, b2, h, 1.f);
  // 10: LN2 -> out (overwrites h)
  ln_row<1><<<dim3(16384), blk, 0, stream>>>(r1, g2, be2, out, nullptr);
}

// Round 3
// 741.301 us; speedup vs baseline: 1.3046x; 1.3046x over previous
//
#include <hip/hip_runtime.h>
#include <hip/hip_bf16.h>

// ---------------------------------------------------------------------------
// MiniTransformer: B=8,S=2048,D=1024,H=2048, fp32 in/out, bf16 MFMA inside.
// All GEMM operands pre-converted to bf16 so staging is pure
// global_load_lds width=16 (m97 structure: 128x128 tile, BK=64, linear LDS).
// Pipeline:
//   0.  cvt: xb = bf16(x); Wqkv_b = bf16(concat(Wq,Wk,Wv)) [3072,1024]
//   1.  gemm EP_QKV:  [q|k|vT] = xb @ Wqkv^T  (one GEMM, N=3072)
//   2.  gemm EP_BF16: scores = q@k^T /32 (per batch)
//   2b. cvt: W1b, W2b (into kb region, dead after step 2)
//   3.  softmax in place (scores -> P)
//   4.  gemm EP_PV:   r1 = P@V + x (fp32)
//   5.  LN1 -> h (fp32, in d_out) + hb (bf16, aliases qb)
//   6.  gemm EP_FF1:  ff1 = relu(hb@W1^T + b1) -> sP
//   7.  gemm EP_FF2:  r1 = ff1@W2^T + b2 + h
//   8.  LN2 -> d_out
// Scratch (234,881,024 B total):
//   qb(BSD bf16, ->hb) | kb(BSD, ->W1b/W2b) | vTb(BSD, (B,D,S)) |
//   sP(BSS bf16, xb alias -> scores -> P -> ff1) | r1(BSD fp32, Wqkv_b alias)
// ---------------------------------------------------------------------------

typedef __attribute__((ext_vector_type(4))) float  f32x4;
typedef __attribute__((ext_vector_type(8))) short  short8;
typedef __attribute__((ext_vector_type(4))) short  short4v;
typedef __attribute__((ext_vector_type(8))) __bf16 bf16x8;
typedef unsigned short ushort_t;

static __device__ __forceinline__ unsigned short f2bf(float f) {
  unsigned u = __builtin_bit_cast(unsigned, f);
  u += 0x7fffu + ((u >> 16) & 1u);  // RNE
  return (unsigned short)(u >> 16);
}
static __device__ __forceinline__ float bf2f(unsigned short u) {
  return __builtin_bit_cast(float, (unsigned)u << 16);
}

#define GLDS16(g, l)                                                        \
  __builtin_amdgcn_global_load_lds(                                         \
      (const __attribute__((address_space(1))) void*)(g),                   \
      (__attribute__((address_space(3))) void*)(l), 16, 0, 0)

// ---------------------------------------------------------------------------
// fp32 -> bf16 conversion, 8 elems/thread. n must be a multiple of 8.
// ---------------------------------------------------------------------------
__global__ __launch_bounds__(256) void cvt_f32_bf16(
    const float* __restrict__ in, ushort_t* __restrict__ out, long n) {
  long i = ((long)blockIdx.x * 256 + threadIdx.x) * 8;
  if (i >= n) return;
  f32x4 a = *(const f32x4*)(in + i);
  f32x4 b = *(const f32x4*)(in + i + 4);
  short8 t;
  t[0] = (short)f2bf(a.x); t[1] = (short)f2bf(a.y);
  t[2] = (short)f2bf(a.z); t[3] = (short)f2bf(a.w);
  t[4] = (short)f2bf(b.x); t[5] = (short)f2bf(b.y);
  t[6] = (short)f2bf(b.z); t[7] = (short)f2bf(b.w);
  *(short8*)(out + i) = t;
}

// ---------------------------------------------------------------------------
// GEMM: C[M,N] = A[M,K] @ B[N,K]^T, all-bf16 operands, fp32 accum.
// 128x128 tile, BK=64, 256 thr = 4 waves (2x2), mfma_f32_16x16x32_bf16.
// Staging: global_load_lds dwordx4 into LINEAR LDS [128][64] bf16.
// (T2 swizzle intentionally omitted: null at 2-phase per regime gate.)
// ---------------------------------------------------------------------------
enum { EP_QKV = 0, EP_BF16 = 1, EP_PV = 2, EP_FF1 = 3, EP_FF2 = 4 };

constexpr long BSDc = 8L * 2048 * 1024;

template <int EPI>
__global__ __launch_bounds__(256) void gemm_bt(
    const ushort_t* __restrict__ A, const ushort_t* __restrict__ B,
    void* __restrict__ C, int N, int K, long sA, long sB, long sC, long sRes,
    const float* __restrict__ bias, const float* __restrict__ res,
    float scale) {
  __shared__ __align__(16) ushort_t As[128 * 64];
  __shared__ __align__(16) ushort_t Bs[128 * 64];
  const int tid  = threadIdx.x;
  const int lane = tid & 63;
  const int w    = tid >> 6;
  const int wr   = (w >> 1) * 64, wc = (w & 1) * 64;
  const long bz  = blockIdx.z;
  const long m0  = (long)blockIdx.x * 128;
  const long n0  = (long)blockIdx.y * 128;
  const ushort_t* Ab = A + bz * sA;
  const ushort_t* Bb = B + bz * sB;

  f32x4 acc[4][4] = {};

  for (int k0 = 0; k0 < K; k0 += 64) {
    __syncthreads();
    // Stage A,B tiles: 1024 chunks x 16B each; chunk c = (row=c>>3, col8=(c&7)).
    // LDS dest is wave-uniform base + lane*16 (HW rule); lane order matches
    // the linear chunk order, so layout is linear row-major [128][64].
#pragma unroll
    for (int it = 0; it < 4; ++it) {
      int c = tid + it * 256;
      const ushort_t* ga = Ab + (m0 + (c >> 3)) * (long)K + k0 + ((c & 7) << 3);
      GLDS16(ga, As + ((it * 256 + w * 64) << 3));
    }
#pragma unroll
    for (int it = 0; it < 4; ++it) {
      int c = tid + it * 256;
      const ushort_t* gb = Bb + (n0 + (c >> 3)) * (long)K + k0 + ((c & 7) << 3);
      GLDS16(gb, Bs + ((it * 256 + w * 64) << 3));
    }
    __syncthreads();
#pragma unroll
    for (int kk = 0; kk < 2; ++kk) {
      short8 af[4], bfr[4];
      const int cb = kk * 64 + ((lane >> 4) << 4);
#pragma unroll
      for (int i = 0; i < 4; ++i) {
        int ra = wr + i * 16 + (lane & 15);
        af[i]  = *(const short8*)((const char*)As + (ra << 7) + cb);
        int rb = wc + i * 16 + (lane & 15);
        bfr[i] = *(const short8*)((const char*)Bs + (rb << 7) + cb);
      }
#pragma unroll
      for (int i = 0; i < 4; ++i)
#pragma unroll
        for (int j = 0; j < 4; ++j)
          acc[i][j] = __builtin_amdgcn_mfma_f32_16x16x32_bf16(
              __builtin_bit_cast(bf16x8, af[i]),
              __builtin_bit_cast(bf16x8, bfr[i == i ? j : j]), acc[i][j], 0, 0,
              0);
    }
  }

  // Epilogue. C/D layout: col = lane&15, row = (lane>>4)*4 + reg.
  const int rb0 = ((lane >> 4) << 2);
  const int cl  = (lane & 15);
#pragma unroll
  for (int i = 0; i < 4; ++i) {
#pragma unroll
    for (int j = 0; j < 4; ++j) {
      long gmb = m0 + wr + i * 16 + rb0;
      long gc  = n0 + wc + j * 16 + cl;
      if constexpr (EPI == EP_QKV) {
        long which = gc >> 10;   // 0=q, 1=k, 2=v   (uniform per block)
        long col   = gc & 1023;
        if (which == 2) {
          // vT layout (B,D,S): contiguous in s across the 4 acc regs.
          long bb = gmb >> 11, s = gmb & 2047;
          short4v pk;
#pragma unroll
          for (int r = 0; r < 4; ++r) pk[r] = (short)f2bf(acc[i][j][r]);
          *(short4v*)((ushort_t*)C + 2 * BSDc + ((bb << 10) + col) * 2048 + s) =
              pk;
        } else {
#pragma unroll
          for (int r = 0; r < 4; ++r)
            ((ushort_t*)C)[which * BSDc + (gmb + r) * 1024 + col] =
                f2bf(acc[i][j][r]);
        }
      } else {
#pragma unroll
        for (int r = 0; r < 4; ++r) {
          long gm = gmb + r;
          float v = acc[i][j][r] * scale;
          if constexpr (EPI == EP_BF16) {
            ((ushort_t*)C)[bz * sC + gm * N + gc] = f2bf(v);
          } else if constexpr (EPI == EP_PV) {
            v += res[bz * sRes + gm * N + gc];
            ((float*)C)[bz * sC + gm * N + gc] = v;
          } else if constexpr (EPI == EP_FF1) {
            v += bias[gc];
            v = v > 0.f ? v : 0.f;
            ((ushort_t*)C)[gm * N + gc] = f2bf(v);
          } else {  // EP_FF2
            v += bias[gc] + res[gm * N + gc];
            ((float*)C)[gm * N + gc] = v;
          }
        }
      }
    }
  }
}

// ---------------------------------------------------------------------------
// Row softmax, in place on bf16 (B*S rows of 2048). 256 thr, 8 el/thread.
// ---------------------------------------------------------------------------
__global__ __launch_bounds__(256) void softmax_inplace(
    ushort_t* __restrict__ P) {
  __shared__ float rmax[4], rsum[4];
  const int tid   = threadIdx.x;
  const long base = (long)blockIdx.x * 2048;
  short8 sv = *(const short8*)(P + base + tid * 8);
  float v[8];
#pragma unroll
  for (int j = 0; j < 8; ++j) v[j] = bf2f((unsigned short)sv[j]);
  float mx = v[0];
#pragma unroll
  for (int j = 1; j < 8; ++j) mx = fmaxf(mx, v[j]);
#pragma unroll
  for (int off = 32; off; off >>= 1) mx = fmaxf(mx, __shfl_down(mx, off, 64));
  if ((tid & 63) == 0) rmax[tid >> 6] = mx;
  __syncthreads();
  mx = fmaxf(fmaxf(rmax[0], rmax[1]), fmaxf(rmax[2], rmax[3]));
  float s = 0.f;
#pragma unroll
  for (int j = 0; j < 8; ++j) {
    v[j] = __expf(v[j] - mx);
    s += v[j];
  }
#pragma unroll
  for (int off = 32; off; off >>= 1) s += __shfl_down(s, off, 64);
  if ((tid & 63) == 0) rsum[tid >> 6] = s;
  __syncthreads();
  s = (rsum[0] + rsum[1]) + (rsum[2] + rsum[3]);
  float inv = 1.f / s;
  short8 o;
#pragma unroll
  for (int j = 0; j < 8; ++j) o[j] = (short)f2bf(v[j] * inv);
  *(short8*)(P + base + tid * 8) = o;
}

// ---------------------------------------------------------------------------
// Row LayerNorm over D=1024. MODE 0: write fp32 + bf16; MODE 1: fp32 only.
// ---------------------------------------------------------------------------
template <int MODE>
__global__ __launch_bounds__(256) void ln_row(const float* __restrict__ X,
                                              const float* __restrict__ g,
                                              const float* __restrict__ be,
                                              float* __restrict__ Yf,
                                              ushort_t* __restrict__ Yb) {
  __shared__ float rs[4], rq[4];
  const int tid   = threadIdx.x;
  const long base = (long)blockIdx.x << 10;
  f32x4 v = *(const f32x4*)(X + base + tid * 4);
  float s = v.x + v.y + v.z + v.w;
  float q = v.x * v.x + v.y * v.y + v.z * v.z + v.w * v.w;
#pragma unroll
  for (int off = 32; off; off >>= 1) {
    s += __shfl_down(s, off, 64);
    q += __shfl_down(q, off, 64);
  }
  if ((tid & 63) == 0) {
    rs[tid >> 6] = s;
    rq[tid >> 6] = q;
  }
  __syncthreads();
  s = (rs[0] + rs[1]) + (rs[2] + rs[3]);
  q = (rq[0] + rq[1]) + (rq[2] + rq[3]);
  float mu   = s * (1.f / 1024.f);
  float var  = q * (1.f / 1024.f) - mu * mu;
  float rstd = rsqrtf(var + 1e-5f);
  int c    = tid * 4;
  f32x4 gg = *(const f32x4*)(g + c);
  f32x4 bb = *(const f32x4*)(be + c);
  f32x4 y;
  y.x = (v.x - mu) * rstd * gg.x + bb.x;
  y.y = (v.y - mu) * rstd * gg.y + bb.y;
  y.z = (v.z - mu) * rstd * gg.z + bb.z;
  y.w = (v.w - mu) * rstd * gg.w + bb.w;
  *(f32x4*)(Yf + base + c) = y;
  if constexpr (MODE == 0) {
    short4v ob;
    ob[0] = (short)f2bf(y.x);
    ob[1] = (short)f2bf(y.y);
    ob[2] = (short)f2bf(y.z);
    ob[3] = (short)f2bf(y.w);
    *(short4v*)(Yb + base + c) = ob;
  }
}

// ---------------------------------------------------------------------------
extern "C" void kernel_launch(void* const* d_in, const int* in_sizes, int n_in,
                              void* d_out, int out_size, void* d_ws,
                              size_t ws_size, hipStream_t stream) {
  const float* x   = (const float*)d_in[0];
  const float* Wq  = (const float*)d_in[1];
  const float* Wk  = (const float*)d_in[2];
  const float* Wv  = (const float*)d_in[3];
  const float* W1  = (const float*)d_in[4];
  const float* b1  = (const float*)d_in[5];
  const float* W2  = (const float*)d_in[6];
  const float* b2  = (const float*)d_in[7];
  const float* g1  = (const float*)d_in[8];
  const float* be1 = (const float*)d_in[9];
  const float* g2  = (const float*)d_in[10];
  const float* be2 = (const float*)d_in[11];
  float* out = (float*)d_out;

  constexpr long BSD = 8L * 2048 * 1024;  // 16,777,216 elems
  constexpr long BSS = 8L * 2048 * 2048;  // 33,554,432 elems
  constexpr long DD  = 1024L * 1024;      // 1,048,576
  constexpr long HD  = 2048L * 1024;      // 2,097,152

  // Scratch: qb | kb | vTb | sP | r1  = 234,881,024 bytes total.
  ushort_t* qb  = (ushort_t*)d_ws;   // q; reused as hb after scores GEMM
  ushort_t* kb  = qb + BSD;          // k; reused as W1b/W2b after scores GEMM
  ushort_t* vTb = kb + BSD;          // (B,D,S)
  ushort_t* sP  = vTb + BSD;         // xb -> scores -> P -> ff1 (BSS)
  float*    r1  = (float*)(sP + BSS);  // Wqkv_b alias -> attn+x -> res2 (BSD)

  ushort_t* xb   = sP;               // dead before scores written
  ushort_t* Wqkvb = (ushort_t*)r1;   // [3072,1024] bf16; dead before PV writes
  ushort_t* W1b  = kb;               // converted after scores GEMM
  ushort_t* W2b  = kb + HD;
  ushort_t* hb   = qb;
  float*    h    = out;              // d_out dead until LN2 rewrites it

  dim3 blk(256);
  const long SD = 2048L * 1024, SS = 2048L * 2048, DS = 1024L * 2048;

  // 0: conversions (xb, Wq|Wk|Wv concatenated -> [3072,1024] bf16)
  cvt_f32_bf16<<<dim3(8192), blk, 0, stream>>>(x, xb, BSD);
  cvt_f32_bf16<<<dim3(512), blk, 0, stream>>>(Wq, Wqkvb, DD);
  cvt_f32_bf16<<<dim3(512), blk, 0, stream>>>(Wk, Wqkvb + DD, DD);
  cvt_f32_bf16<<<dim3(512), blk, 0, stream>>>(Wv, Wqkvb + 2 * DD, DD);
  // 1: fused QKV projection (M=16384, N=3072, K=1024)
  gemm_bt<EP_QKV><<<dim3(128, 24, 1), blk, 0, stream>>>(
      xb, Wqkvb, qb, 3072, 1024, 0, 0, 0, 0, nullptr, nullptr, 1.f);
  // 2: scores = q@k^T / 32 (per batch: M=N=2048, K=1024)
  gemm_bt<EP_BF16><<<dim3(16, 16, 8), blk, 0, stream>>>(
      qb, kb, sP, 2048, 1024, SD, SD, SS, 0, nullptr, nullptr, 0.03125f);
  // 2b: convert FFN weights into kb region (kb dead now)
  cvt_f32_bf16<<<dim3(1024), blk, 0, stream>>>(W1, W1b, HD);
  cvt_f32_bf16<<<dim3(1024), blk, 0, stream>>>(W2, W2b, HD);
  // 3: softmax
  softmax_inplace<<<dim3(16384), blk, 0, stream>>>(sP);
  // 4: attn_out + x (per batch: M=2048, N=1024, K=2048)
  gemm_bt<EP_PV><<<dim3(16, 8, 8), blk, 0, stream>>>(
      sP, vTb, r1, 1024, 2048, SS, DS, SD, SD, nullptr, x, 1.f);
  // 5: LN1 -> h (fp32, in d_out) + hb (bf16, aliases qb)
  ln_row<0><<<dim3(16384), blk, 0, stream>>>(r1, g1, be1, h, hb);
  // 6: ff1 = relu(hb@W1^T + b1) (M=16384, N=2048, K=1024)
  gemm_bt<EP_FF1><<<dim3(128, 16, 1), blk, 0, stream>>>(
      hb, W1b, sP, 2048, 1024, 0, 0, 0, 0, b1, nullptr, 1.f);
  // 7: res2 = ff1@W2^T + b2 + h (M=16384, N=1024, K=2048)
  gemm_bt<EP_FF2><<<dim3(128, 8, 1), blk, 0, stream>>>(
      sP, W2b, r1, 1024, 2048, 0, 0, 0, 0, b2, h, 1.f);
  // 8: LN2 -> out (overwrites h)
  ln_row<1><<<dim3(16384), blk, 0, stream>>>(r1, g2, be2, out, nullptr);
}

// Round 4
// 646.974 us; speedup vs baseline: 1.4948x; 1.1458x over previous
//
#include <hip/hip_runtime.h>
#include <hip/hip_bf16.h>

// ---------------------------------------------------------------------------
// MiniTransformer: B=8,S=2048,D=1024,H=2048, fp32 in/out, bf16 MFMA inside.
// GEMM staging is pure global_load_lds width=16 into a CONFLICT-FREE linear
// LDS layout [kk][128 rows][32 k] (frag ds_read_b128 covers a dense 1KB
// window -> 2 lanes/bank = free; no swizzle needed, gload_lds-compatible).
// Pipeline:
//   0.  cvt: xb = bf16(x); Wqkv_b = bf16(concat(Wq,Wk,Wv)) [3072,1024]
//   1.  gemm EP_QKV:  [q|k|vT] = xb @ Wqkv^T  (one GEMM, N=3072)
//   2.  gemm EP_BF16: scores = q@k^T /32 (per batch)
//   2b. cvt: W1b, W2b (into kb region, dead after step 2)
//   3.  softmax in place (scores -> P)
//   4.  gemm EP_PV:   r1 = P@V + x (fp32)
//   5.  LN1 -> h (fp32, in d_out) + hb (bf16, aliases qb)
//   6.  gemm EP_FF1:  ff1 = relu(hb@W1^T + b1) -> sP
//   7.  gemm EP_FF2:  r1 = ff1@W2^T + b2 + h
//   8.  LN2 -> d_out
// Scratch (234,881,024 B total):
//   qb(BSD bf16, ->hb) | kb(BSD, ->W1b/W2b) | vTb(BSD, (B,D,S)) |
//   sP(BSS bf16, xb alias -> scores -> P -> ff1) | r1(BSD fp32, Wqkv_b alias)
// ---------------------------------------------------------------------------

typedef __attribute__((ext_vector_type(4))) float  f32x4;
typedef __attribute__((ext_vector_type(8))) short  short8;
typedef __attribute__((ext_vector_type(4))) short  short4v;
typedef __attribute__((ext_vector_type(8))) __bf16 bf16x8;
typedef unsigned short ushort_t;

static __device__ __forceinline__ unsigned short f2bf(float f) {
  unsigned u = __builtin_bit_cast(unsigned, f);
  u += 0x7fffu + ((u >> 16) & 1u);  // RNE
  return (unsigned short)(u >> 16);
}
static __device__ __forceinline__ float bf2f(unsigned short u) {
  return __builtin_bit_cast(float, (unsigned)u << 16);
}

#define GLDS16(g, l)                                                        \
  __builtin_amdgcn_global_load_lds(                                         \
      (const __attribute__((address_space(1))) void*)(g),                   \
      (__attribute__((address_space(3))) void*)(l), 16, 0, 0)

// ---------------------------------------------------------------------------
// fp32 -> bf16 conversion, 8 elems/thread. n must be a multiple of 8.
// ---------------------------------------------------------------------------
__global__ __launch_bounds__(256) void cvt_f32_bf16(
    const float* __restrict__ in, ushort_t* __restrict__ out, long n) {
  long i = ((long)blockIdx.x * 256 + threadIdx.x) * 8;
  if (i >= n) return;
  f32x4 a = *(const f32x4*)(in + i);
  f32x4 b = *(const f32x4*)(in + i + 4);
  short8 t;
  t[0] = (short)f2bf(a.x); t[1] = (short)f2bf(a.y);
  t[2] = (short)f2bf(a.z); t[3] = (short)f2bf(a.w);
  t[4] = (short)f2bf(b.x); t[5] = (short)f2bf(b.y);
  t[6] = (short)f2bf(b.z); t[7] = (short)f2bf(b.w);
  *(short8*)(out + i) = t;
}

// ---------------------------------------------------------------------------
// GEMM: C[M,N] = A[M,K] @ B[N,K]^T, all-bf16 operands, fp32 accum.
// 128x128 tile, BK=64, 256 thr = 4 waves (2x2), mfma_f32_16x16x32_bf16.
// LDS: [kk:2][row:128][k:32] bf16 per operand (16KB each, 32KB total).
//   chunk c (16B) = kk*512 + row*4 + ks ; staged linearly by global_load_lds
//   (dest = wave base + lane*16), per-lane GLOBAL addr does the layout.
// Frag read: byte = kk*8192 + row*64 + (lane>>4)*16 -> dense 1KB window per
//   wave read -> 2 lanes/bank -> conflict-free.
// ---------------------------------------------------------------------------
enum { EP_QKV = 0, EP_BF16 = 1, EP_PV = 2, EP_FF1 = 3, EP_FF2 = 4 };

constexpr long BSDc = 8L * 2048 * 1024;

template <int EPI>
__global__ __launch_bounds__(256) void gemm_bt(
    const ushort_t* __restrict__ A, const ushort_t* __restrict__ B,
    void* __restrict__ C, int N, int K, long sA, long sB, long sC, long sRes,
    const float* __restrict__ bias, const float* __restrict__ res,
    float scale) {
  __shared__ __align__(16) ushort_t As[2 * 128 * 32];
  __shared__ __align__(16) ushort_t Bs[2 * 128 * 32];
  const int tid  = threadIdx.x;
  const int lane = tid & 63;
  const int w    = tid >> 6;
  const int wr   = (w >> 1) * 64, wc = (w & 1) * 64;
  const long bz  = blockIdx.z;
  const long m0  = (long)blockIdx.x * 128;
  const long n0  = (long)blockIdx.y * 128;
  const ushort_t* Ab = A + bz * sA;
  const ushort_t* Bb = B + bz * sB;

  // Per-thread staging source offsets (element units, k0 added per iter).
  // Chunk c -> (kk = c>>9, row = (c&511)>>2, ks = c&3); global elem offset
  // = row*K + kk*32 + ks*8.
  long aoff[4], boff[4];
#pragma unroll
  for (int it = 0; it < 4; ++it) {
    int c   = tid + it * 256;
    int kk  = c >> 9;
    int row = (c & 511) >> 2;
    int ks  = c & 3;
    aoff[it] = (m0 + row) * (long)K + kk * 32 + ks * 8;
    boff[it] = (n0 + row) * (long)K + kk * 32 + ks * 8;
  }

  f32x4 acc[4][4] = {};

  for (int k0 = 0; k0 < K; k0 += 64) {
    __syncthreads();
#pragma unroll
    for (int it = 0; it < 4; ++it)
      GLDS16(Ab + aoff[it] + k0, As + ((it * 256 + w * 64) << 3));
#pragma unroll
    for (int it = 0; it < 4; ++it)
      GLDS16(Bb + boff[it] + k0, Bs + ((it * 256 + w * 64) << 3));
    __syncthreads();
#pragma unroll
    for (int kk = 0; kk < 2; ++kk) {
      short8 af[4], bfr[4];
      const int ksb = ((lane >> 4) << 4);  // k-slot byte offset within row
#pragma unroll
      for (int i = 0; i < 4; ++i) {
        int ra = wr + i * 16 + (lane & 15);
        af[i]  = *(const short8*)((const char*)As + kk * 8192 + (ra << 6) + ksb);
        int rb = wc + i * 16 + (lane & 15);
        bfr[i] = *(const short8*)((const char*)Bs + kk * 8192 + (rb << 6) + ksb);
      }
#pragma unroll
      for (int i = 0; i < 4; ++i)
#pragma unroll
        for (int j = 0; j < 4; ++j)
          acc[i][j] = __builtin_amdgcn_mfma_f32_16x16x32_bf16(
              __builtin_bit_cast(bf16x8, af[i]),
              __builtin_bit_cast(bf16x8, bfr[j]), acc[i][j], 0, 0, 0);
    }
  }

  // Epilogue. C/D layout: col = lane&15, row = (lane>>4)*4 + reg.
  const int rb0 = ((lane >> 4) << 2);
  const int cl  = (lane & 15);
#pragma unroll
  for (int i = 0; i < 4; ++i) {
#pragma unroll
    for (int j = 0; j < 4; ++j) {
      long gmb = m0 + wr + i * 16 + rb0;
      long gc  = n0 + wc + j * 16 + cl;
      if constexpr (EPI == EP_QKV) {
        long which = gc >> 10;   // 0=q, 1=k, 2=v   (uniform per block)
        long col   = gc & 1023;
        if (which == 2) {
          // vT layout (B,D,S): contiguous in s across the 4 acc regs.
          long bb = gmb >> 11, s = gmb & 2047;
          short4v pk;
#pragma unroll
          for (int r = 0; r < 4; ++r) pk[r] = (short)f2bf(acc[i][j][r]);
          *(short4v*)((ushort_t*)C + 2 * BSDc + ((bb << 10) + col) * 2048 + s) =
              pk;
        } else {
#pragma unroll
          for (int r = 0; r < 4; ++r)
            ((ushort_t*)C)[which * BSDc + (gmb + r) * 1024 + col] =
                f2bf(acc[i][j][r]);
        }
      } else {
#pragma unroll
        for (int r = 0; r < 4; ++r) {
          long gm = gmb + r;
          float v = acc[i][j][r] * scale;
          if constexpr (EPI == EP_BF16) {
            ((ushort_t*)C)[bz * sC + gm * N + gc] = f2bf(v);
          } else if constexpr (EPI == EP_PV) {
            v += res[bz * sRes + gm * N + gc];
            ((float*)C)[bz * sC + gm * N + gc] = v;
          } else if constexpr (EPI == EP_FF1) {
            v += bias[gc];
            v = v > 0.f ? v : 0.f;
            ((ushort_t*)C)[gm * N + gc] = f2bf(v);
          } else {  // EP_FF2
            v += bias[gc] + res[gm * N + gc];
            ((float*)C)[gm * N + gc] = v;
          }
        }
      }
    }
  }
}

// ---------------------------------------------------------------------------
// Row softmax, in place on bf16 (B*S rows of 2048). 256 thr, 8 el/thread.
// ---------------------------------------------------------------------------
__global__ __launch_bounds__(256) void softmax_inplace(
    ushort_t* __restrict__ P) {
  __shared__ float rmax[4], rsum[4];
  const int tid   = threadIdx.x;
  const long base = (long)blockIdx.x * 2048;
  short8 sv = *(const short8*)(P + base + tid * 8);
  float v[8];
#pragma unroll
  for (int j = 0; j < 8; ++j) v[j] = bf2f((unsigned short)sv[j]);
  float mx = v[0];
#pragma unroll
  for (int j = 1; j < 8; ++j) mx = fmaxf(mx, v[j]);
#pragma unroll
  for (int off = 32; off; off >>= 1) mx = fmaxf(mx, __shfl_down(mx, off, 64));
  if ((tid & 63) == 0) rmax[tid >> 6] = mx;
  __syncthreads();
  mx = fmaxf(fmaxf(rmax[0], rmax[1]), fmaxf(rmax[2], rmax[3]));
  float s = 0.f;
#pragma unroll
  for (int j = 0; j < 8; ++j) {
    v[j] = __expf(v[j] - mx);
    s += v[j];
  }
#pragma unroll
  for (int off = 32; off; off >>= 1) s += __shfl_down(s, off, 64);
  if ((tid & 63) == 0) rsum[tid >> 6] = s;
  __syncthreads();
  s = (rsum[0] + rsum[1]) + (rsum[2] + rsum[3]);
  float inv = 1.f / s;
  short8 o;
#pragma unroll
  for (int j = 0; j < 8; ++j) o[j] = (short)f2bf(v[j] * inv);
  *(short8*)(P + base + tid * 8) = o;
}

// ---------------------------------------------------------------------------
// Row LayerNorm over D=1024. MODE 0: write fp32 + bf16; MODE 1: fp32 only.
// ---------------------------------------------------------------------------
template <int MODE>
__global__ __launch_bounds__(256) void ln_row(const float* __restrict__ X,
                                              const float* __restrict__ g,
                                              const float* __restrict__ be,
                                              float* __restrict__ Yf,
                                              ushort_t* __restrict__ Yb) {
  __shared__ float rs[4], rq[4];
  const int tid   = threadIdx.x;
  const long base = (long)blockIdx.x << 10;
  f32x4 v = *(const f32x4*)(X + base + tid * 4);
  float s = v.x + v.y + v.z + v.w;
  float q = v.x * v.x + v.y * v.y + v.z * v.z + v.w * v.w;
#pragma unroll
  for (int off = 32; off; off >>= 1) {
    s += __shfl_down(s, off, 64);
    q += __shfl_down(q, off, 64);
  }
  if ((tid & 63) == 0) {
    rs[tid >> 6] = s;
    rq[tid >> 6] = q;
  }
  __syncthreads();
  s = (rs[0] + rs[1]) + (rs[2] + rs[3]);
  q = (rq[0] + rq[1]) + (rq[2] + rq[3]);
  float mu   = s * (1.f / 1024.f);
  float var  = q * (1.f / 1024.f) - mu * mu;
  float rstd = rsqrtf(var + 1e-5f);
  int c    = tid * 4;
  f32x4 gg = *(const f32x4*)(g + c);
  f32x4 bb = *(const f32x4*)(be + c);
  f32x4 y;
  y.x = (v.x - mu) * rstd * gg.x + bb.x;
  y.y = (v.y - mu) * rstd * gg.y + bb.y;
  y.z = (v.z - mu) * rstd * gg.z + bb.z;
  y.w = (v.w - mu) * rstd * gg.w + bb.w;
  *(f32x4*)(Yf + base + c) = y;
  if constexpr (MODE == 0) {
    short4v ob;
    ob[0] = (short)f2bf(y.x);
    ob[1] = (short)f2bf(y.y);
    ob[2] = (short)f2bf(y.z);
    ob[3] = (short)f2bf(y.w);
    *(short4v*)(Yb + base + c) = ob;
  }
}

// ---------------------------------------------------------------------------
extern "C" void kernel_launch(void* const* d_in, const int* in_sizes, int n_in,
                              void* d_out, int out_size, void* d_ws,
                              size_t ws_size, hipStream_t stream) {
  const float* x   = (const float*)d_in[0];
  const float* Wq  = (const float*)d_in[1];
  const float* Wk  = (const float*)d_in[2];
  const float* Wv  = (const float*)d_in[3];
  const float* W1  = (const float*)d_in[4];
  const float* b1  = (const float*)d_in[5];
  const float* W2  = (const float*)d_in[6];
  const float* b2  = (const float*)d_in[7];
  const float* g1  = (const float*)d_in[8];
  const float* be1 = (const float*)d_in[9];
  const float* g2  = (const float*)d_in[10];
  const float* be2 = (const float*)d_in[11];
  float* out = (float*)d_out;

  constexpr long BSD = 8L * 2048 * 1024;  // 16,777,216 elems
  constexpr long BSS = 8L * 2048 * 2048;  // 33,554,432 elems
  constexpr long DD  = 1024L * 1024;      // 1,048,576
  constexpr long HD  = 2048L * 1024;      // 2,097,152

  // Scratch: qb | kb | vTb | sP | r1  = 234,881,024 bytes total.
  ushort_t* qb  = (ushort_t*)d_ws;   // q; reused as hb after scores GEMM
  ushort_t* kb  = qb + BSD;          // k; reused as W1b/W2b after scores GEMM
  ushort_t* vTb = kb + BSD;          // (B,D,S)
  ushort_t* sP  = vTb + BSD;         // xb -> scores -> P -> ff1 (BSS)
  float*    r1  = (float*)(sP + BSS);  // Wqkv_b alias -> attn+x -> res2 (BSD)

  ushort_t* xb   = sP;               // dead before scores written
  ushort_t* Wqkvb = (ushort_t*)r1;   // [3072,1024] bf16; dead before PV writes
  ushort_t* W1b  = kb;               // converted after scores GEMM
  ushort_t* W2b  = kb + HD;
  ushort_t* hb   = qb;
  float*    h    = out;              // d_out dead until LN2 rewrites it

  dim3 blk(256);
  const long SD = 2048L * 1024, SS = 2048L * 2048, DS = 1024L * 2048;

  // 0: conversions (xb, Wq|Wk|Wv concatenated -> [3072,1024] bf16)
  cvt_f32_bf16<<<dim3(8192), blk, 0, stream>>>(x, xb, BSD);
  cvt_f32_bf16<<<dim3(512), blk, 0, stream>>>(Wq, Wqkvb, DD);
  cvt_f32_bf16<<<dim3(512), blk, 0, stream>>>(Wk, Wqkvb + DD, DD);
  cvt_f32_bf16<<<dim3(512), blk, 0, stream>>>(Wv, Wqkvb + 2 * DD, DD);
  // 1: fused QKV projection (M=16384, N=3072, K=1024)
  gemm_bt<EP_QKV><<<dim3(128, 24, 1), blk, 0, stream>>>(
      xb, Wqkvb, qb, 3072, 1024, 0, 0, 0, 0, nullptr, nullptr, 1.f);
  // 2: scores = q@k^T / 32 (per batch: M=N=2048, K=1024)
  gemm_bt<EP_BF16><<<dim3(16, 16, 8), blk, 0, stream>>>(
      qb, kb, sP, 2048, 1024, SD, SD, SS, 0, nullptr, nullptr, 0.03125f);
  // 2b: convert FFN weights into kb region (kb dead now)
  cvt_f32_bf16<<<dim3(1024), blk, 0, stream>>>(W1, W1b, HD);
  cvt_f32_bf16<<<dim3(1024), blk, 0, stream>>>(W2, W2b, HD);
  // 3: softmax
  softmax_inplace<<<dim3(16384), blk, 0, stream>>>(sP);
  // 4: attn_out + x (per batch: M=2048, N=1024, K=2048)
  gemm_bt<EP_PV><<<dim3(16, 8, 8), blk, 0, stream>>>(
      sP, vTb, r1, 1024, 2048, SS, DS, SD, SD, nullptr, x, 1.f);
  // 5: LN1 -> h (fp32, in d_out) + hb (bf16, aliases qb)
  ln_row<0><<<dim3(16384), blk, 0, stream>>>(r1, g1, be1, h, hb);
  // 6: ff1 = relu(hb@W1^T + b1) (M=16384, N=2048, K=1024)
  gemm_bt<EP_FF1><<<dim3(128, 16, 1), blk, 0, stream>>>(
      hb, W1b, sP, 2048, 1024, 0, 0, 0, 0, b1, nullptr, 1.f);
  // 7: res2 = ff1@W2^T + b2 + h (M=16384, N=1024, K=2048)
  gemm_bt<EP_FF2><<<dim3(128, 8, 1), blk, 0, stream>>>(
      sP, W2b, r1, 1024, 2048, 0, 0, 0, 0, b2, h, 1.f);
  // 8: LN2 -> out (overwrites h)
  ln_row<1><<<dim3(16384), blk, 0, stream>>>(r1, g2, be2, out, nullptr);
}

// Round 5
// 573.505 us; speedup vs baseline: 1.6863x; 1.1281x over previous
//
#include <hip/hip_runtime.h>
#include <hip/hip_bf16.h>

// ---------------------------------------------------------------------------
// MiniTransformer: B=8,S=2048,D=1024,H=2048, fp32 in/out, bf16 MFMA inside.
// GEMM: 256x256 tile, BK=32, 8 waves (2Mx4N), double-buffered LDS,
// counted s_waitcnt vmcnt(4) (never 0 in loop), raw s_barrier, setprio(1)
// around MFMA cluster. Staging = global_load_lds w16, linear dest, with the
// conflict-free involutive chunk-XOR applied to the per-lane GLOBAL source:
//   LDS half-tile = [64 ldsrows][128B]; element (r,k) at
//   ldsrow=r>>1 (2 tile rows per LDS row), chunk slot=((r&1)*4+(k>>3))^(ldsrow&7)
//   -> every wave ds_read_b128 hits each bank exactly 8x (structural min).
// Pipeline:
//   0.  cvt: xb = bf16(x); Wqkv_b = bf16(concat(Wq,Wk,Wv)) [3072,1024]
//   1.  gemm EP_QKV:  [q|k|vT] = xb @ Wqkv^T  (one GEMM, N=3072)
//   2.  gemm EP_BF16: scores = q@k^T /32 (per batch)
//   2b. cvt: W1b, W2b (into kb region, dead after step 2)
//   3.  softmax in place (scores -> P)
//   4.  gemm EP_PV:   r1 = P@V + x (fp32)
//   5.  LN1 -> h (fp32, in d_out) + hb (bf16, aliases qb)
//   6.  gemm EP_FF1:  ff1 = relu(hb@W1^T + b1) -> sP
//   7.  gemm EP_FF2:  r1 = ff1@W2^T + b2 + h
//   8.  LN2 -> d_out
// Scratch (234,881,024 B): qb|kb|vTb|sP|r1 as before.
// ---------------------------------------------------------------------------

typedef __attribute__((ext_vector_type(4))) float  f32x4;
typedef __attribute__((ext_vector_type(8))) short  short8;
typedef __attribute__((ext_vector_type(4))) short  short4v;
typedef __attribute__((ext_vector_type(8))) __bf16 bf16x8;
typedef unsigned short ushort_t;

static __device__ __forceinline__ unsigned short f2bf(float f) {
  unsigned u = __builtin_bit_cast(unsigned, f);
  u += 0x7fffu + ((u >> 16) & 1u);  // RNE
  return (unsigned short)(u >> 16);
}
static __device__ __forceinline__ float bf2f(unsigned short u) {
  return __builtin_bit_cast(float, (unsigned)u << 16);
}

#define GLDS16(g, l)                                                        \
  __builtin_amdgcn_global_load_lds(                                         \
      (const __attribute__((address_space(1))) void*)(g),                   \
      (__attribute__((address_space(3))) void*)(l), 16, 0, 0)

// ---------------------------------------------------------------------------
// fp32 -> bf16 conversion, 8 elems/thread.
// ---------------------------------------------------------------------------
__global__ __launch_bounds__(256) void cvt_f32_bf16(
    const float* __restrict__ in, ushort_t* __restrict__ out, long n) {
  long i = ((long)blockIdx.x * 256 + threadIdx.x) * 8;
  if (i >= n) return;
  f32x4 a = *(const f32x4*)(in + i);
  f32x4 b = *(const f32x4*)(in + i + 4);
  short8 t;
  t[0] = (short)f2bf(a.x); t[1] = (short)f2bf(a.y);
  t[2] = (short)f2bf(a.z); t[3] = (short)f2bf(a.w);
  t[4] = (short)f2bf(b.x); t[5] = (short)f2bf(b.y);
  t[6] = (short)f2bf(b.z); t[7] = (short)f2bf(b.w);
  *(short8*)(out + i) = t;
}

// ---------------------------------------------------------------------------
// GEMM: C[M,N] = A[M,K] @ B[N,K]^T, bf16 operands, fp32 accum.
// ---------------------------------------------------------------------------
enum { EP_QKV = 0, EP_BF16 = 1, EP_PV = 2, EP_FF1 = 3, EP_FF2 = 4 };

constexpr long BSDc = 8L * 2048 * 1024;

template <int EPI>
__global__ __launch_bounds__(512, 2) void gemm_bt(
    const ushort_t* __restrict__ A, const ushort_t* __restrict__ B,
    void* __restrict__ C, int N, int K, long sA, long sB, long sC, long sRes,
    const float* __restrict__ bias, const float* __restrict__ res,
    float scale) {
  // [dbuf][half(2) x 4096 ushorts] ; 16KB per buf per operand, 64KB total.
  __shared__ __align__(16) ushort_t As[2][8192];
  __shared__ __align__(16) ushort_t Bs[2][8192];
  const int tid  = threadIdx.x;
  const int lane = tid & 63;
  const int w    = tid >> 6;        // 0..7
  const int wm   = w >> 2;          // 0..1 : wave row (128 rows each)
  const int wn   = w & 3;           // 0..3 : wave col (64 cols each)
  const int l15  = lane & 15;
  const int hi   = lane >> 4;       // k-chunk (8 bf16 each)
  const long bz  = blockIdx.z;
  const long m0  = (long)blockIdx.x * 256;
  const long n0  = (long)blockIdx.y * 256;
  const ushort_t* Ab = A + bz * sA;
  const ushort_t* Bb = B + bz * sB;

  // --- staging source offsets (inverse of the read-side XOR swizzle) ---
  // phys chunk cp = w*64+lane within an 8KB half (written linearly by GLDS);
  // natural: ldsrow=cp>>3, slot=(cp&7)^(ldsrow&7), r=2*ldsrow+(slot>>2),
  // k-chunk=slot&3.
  const int cp    = (w << 6) | lane;
  const int lrS   = cp >> 3;
  const int slotS = (cp & 7) ^ (lrS & 7);
  const int rloc  = lrS * 2 + (slotS >> 2);
  const int kchS  = slotS & 3;
  const long aofs0 = (m0 + rloc) * (long)K + kchS * 8;
  const long aofs1 = (m0 + 128 + rloc) * (long)K + kchS * 8;
  const long bofs0 = (n0 + rloc) * (long)K + kchS * 8;
  const long bofs1 = (n0 + 128 + rloc) * (long)K + kchS * 8;

#define STAGE(t, d)                                                         \
  {                                                                         \
    const long kk0 = (long)(t) * 32;                                        \
    GLDS16(Ab + aofs0 + kk0, &As[d][w * 512]);                              \
    GLDS16(Ab + aofs1 + kk0, &As[d][4096 + w * 512]);                       \
    GLDS16(Bb + bofs0 + kk0, &Bs[d][w * 512]);                              \
    GLDS16(Bb + bofs1 + kk0, &Bs[d][4096 + w * 512]);                       \
  }

  // --- read-side swizzled byte offsets (constant per lane) ---
  // A frag i: tile row wm*128 + i*16 + l15, k-bytes hi*16.
  const int slotR = (((l15 & 1) << 2) | hi) ^ (l15 >> 1);
  const int abase = wm * 8192 + (l15 >> 1) * 128 + slotR * 16;
  const int bbase = (wn >> 1) * 8192 +
                    ((wn & 1) * 32 + (l15 >> 1)) * 128 + slotR * 16;

  f32x4 acc[8][4] = {};
  const int NT = K >> 5;

  // Prologue: 2 tiles in flight; wait tile 0 (oldest 4 of 8 loads).
  STAGE(0, 0);
  STAGE(1, 1);
  asm volatile("s_waitcnt vmcnt(4)" ::: "memory");
  __builtin_amdgcn_sched_barrier(0);
  __builtin_amdgcn_s_barrier();

  for (int t = 0; t < NT; ++t) {
    const int d = t & 1;
    // 1) frag ds_reads (12 x ds_read_b128)
    short8 af[8], bq[4];
    const char* Ad = (const char*)&As[d][0];
    const char* Bd = (const char*)&Bs[d][0];
#pragma unroll
    for (int i = 0; i < 8; ++i)
      af[i] = *(const short8*)(Ad + abase + i * 1024);
#pragma unroll
    for (int j = 0; j < 4; ++j)
      bq[j] = *(const short8*)(Bd + bbase + j * 1024);
    // 2) reads complete -> 3) all waves done reading buf d
    asm volatile("s_waitcnt lgkmcnt(0)" ::: "memory");
    __builtin_amdgcn_sched_barrier(0);
    __builtin_amdgcn_s_barrier();
    __builtin_amdgcn_sched_barrier(0);
    // 4) overwrite buf d with tile t+2 (loads fly across the MFMA cluster)
    if (t + 2 < NT) STAGE(t + 2, d);
    // 5) MFMA cluster
    __builtin_amdgcn_s_setprio(1);
#pragma unroll
    for (int i = 0; i < 8; ++i)
#pragma unroll
      for (int j = 0; j < 4; ++j)
        acc[i][j] = __builtin_amdgcn_mfma_f32_16x16x32_bf16(
            __builtin_bit_cast(bf16x8, af[i]), __builtin_bit_cast(bf16x8, bq[j]),
            acc[i][j], 0, 0, 0);
    __builtin_amdgcn_s_setprio(0);
    // 6) tile t+1 ready (counted: leave t+2's 4 loads in flight)
    if (t + 1 < NT) {
      if (t + 2 < NT) {
        asm volatile("s_waitcnt vmcnt(4)" ::: "memory");
      } else {
        asm volatile("s_waitcnt vmcnt(0)" ::: "memory");
      }
      __builtin_amdgcn_sched_barrier(0);
      __builtin_amdgcn_s_barrier();
      __builtin_amdgcn_sched_barrier(0);
    }
  }
#undef STAGE

  // Epilogue. C/D layout: col = lane&15, row = (lane>>4)*4 + reg.
  const int rb0 = hi << 2;
  const int cl  = l15;
#pragma unroll
  for (int i = 0; i < 8; ++i) {
#pragma unroll
    for (int j = 0; j < 4; ++j) {
      long gmb = m0 + wm * 128 + i * 16 + rb0;
      long gc  = n0 + wn * 64 + j * 16 + cl;
      if constexpr (EPI == EP_QKV) {
        long which = gc >> 10;  // 0=q, 1=k, 2=v (uniform per block)
        long col   = gc & 1023;
        if (which == 2) {
          long bb = gmb >> 11, s = gmb & 2047;
          short4v pk;
#pragma unroll
          for (int r = 0; r < 4; ++r) pk[r] = (short)f2bf(acc[i][j][r]);
          *(short4v*)((ushort_t*)C + 2 * BSDc + ((bb << 10) + col) * 2048 + s) =
              pk;
        } else {
#pragma unroll
          for (int r = 0; r < 4; ++r)
            ((ushort_t*)C)[which * BSDc + (gmb + r) * 1024 + col] =
                f2bf(acc[i][j][r]);
        }
      } else {
#pragma unroll
        for (int r = 0; r < 4; ++r) {
          long gm = gmb + r;
          float v = acc[i][j][r] * scale;
          if constexpr (EPI == EP_BF16) {
            ((ushort_t*)C)[bz * sC + gm * N + gc] = f2bf(v);
          } else if constexpr (EPI == EP_PV) {
            v += res[bz * sRes + gm * N + gc];
            ((float*)C)[bz * sC + gm * N + gc] = v;
          } else if constexpr (EPI == EP_FF1) {
            v += bias[gc];
            v = v > 0.f ? v : 0.f;
            ((ushort_t*)C)[gm * N + gc] = f2bf(v);
          } else {  // EP_FF2
            v += bias[gc] + res[gm * N + gc];
            ((float*)C)[gm * N + gc] = v;
          }
        }
      }
    }
  }
}

// ---------------------------------------------------------------------------
// Row softmax, in place on bf16 (B*S rows of 2048). 256 thr, 8 el/thread.
// ---------------------------------------------------------------------------
__global__ __launch_bounds__(256) void softmax_inplace(
    ushort_t* __restrict__ P) {
  __shared__ float rmax[4], rsum[4];
  const int tid   = threadIdx.x;
  const long base = (long)blockIdx.x * 2048;
  short8 sv = *(const short8*)(P + base + tid * 8);
  float v[8];
#pragma unroll
  for (int j = 0; j < 8; ++j) v[j] = bf2f((unsigned short)sv[j]);
  float mx = v[0];
#pragma unroll
  for (int j = 1; j < 8; ++j) mx = fmaxf(mx, v[j]);
#pragma unroll
  for (int off = 32; off; off >>= 1) mx = fmaxf(mx, __shfl_down(mx, off, 64));
  if ((tid & 63) == 0) rmax[tid >> 6] = mx;
  __syncthreads();
  mx = fmaxf(fmaxf(rmax[0], rmax[1]), fmaxf(rmax[2], rmax[3]));
  float s = 0.f;
#pragma unroll
  for (int j = 0; j < 8; ++j) {
    v[j] = __expf(v[j] - mx);
    s += v[j];
  }
#pragma unroll
  for (int off = 32; off; off >>= 1) s += __shfl_down(s, off, 64);
  if ((tid & 63) == 0) rsum[tid >> 6] = s;
  __syncthreads();
  s = (rsum[0] + rsum[1]) + (rsum[2] + rsum[3]);
  float inv = 1.f / s;
  short8 o;
#pragma unroll
  for (int j = 0; j < 8; ++j) o[j] = (short)f2bf(v[j] * inv);
  *(short8*)(P + base + tid * 8) = o;
}

// ---------------------------------------------------------------------------
// Row LayerNorm over D=1024. MODE 0: write fp32 + bf16; MODE 1: fp32 only.
// ---------------------------------------------------------------------------
template <int MODE>
__global__ __launch_bounds__(256) void ln_row(const float* __restrict__ X,
                                              const float* __restrict__ g,
                                              const float* __restrict__ be,
                                              float* __restrict__ Yf,
                                              ushort_t* __restrict__ Yb) {
  __shared__ float rs[4], rq[4];
  const int tid   = threadIdx.x;
  const long base = (long)blockIdx.x << 10;
  f32x4 v = *(const f32x4*)(X + base + tid * 4);
  float s = v.x + v.y + v.z + v.w;
  float q = v.x * v.x + v.y * v.y + v.z * v.z + v.w * v.w;
#pragma unroll
  for (int off = 32; off; off >>= 1) {
    s += __shfl_down(s, off, 64);
    q += __shfl_down(q, off, 64);
  }
  if ((tid & 63) == 0) {
    rs[tid >> 6] = s;
    rq[tid >> 6] = q;
  }
  __syncthreads();
  s = (rs[0] + rs[1]) + (rs[2] + rs[3]);
  q = (rq[0] + rq[1]) + (rq[2] + rq[3]);
  float mu   = s * (1.f / 1024.f);
  float var  = q * (1.f / 1024.f) - mu * mu;
  float rstd = rsqrtf(var + 1e-5f);
  int c    = tid * 4;
  f32x4 gg = *(const f32x4*)(g + c);
  f32x4 bb = *(const f32x4*)(be + c);
  f32x4 y;
  y.x = (v.x - mu) * rstd * gg.x + bb.x;
  y.y = (v.y - mu) * rstd * gg.y + bb.y;
  y.z = (v.z - mu) * rstd * gg.z + bb.z;
  y.w = (v.w - mu) * rstd * gg.w + bb.w;
  *(f32x4*)(Yf + base + c) = y;
  if constexpr (MODE == 0) {
    short4v ob;
    ob[0] = (short)f2bf(y.x);
    ob[1] = (short)f2bf(y.y);
    ob[2] = (short)f2bf(y.z);
    ob[3] = (short)f2bf(y.w);
    *(short4v*)(Yb + base + c) = ob;
  }
}

// ---------------------------------------------------------------------------
extern "C" void kernel_launch(void* const* d_in, const int* in_sizes, int n_in,
                              void* d_out, int out_size, void* d_ws,
                              size_t ws_size, hipStream_t stream) {
  const float* x   = (const float*)d_in[0];
  const float* Wq  = (const float*)d_in[1];
  const float* Wk  = (const float*)d_in[2];
  const float* Wv  = (const float*)d_in[3];
  const float* W1  = (const float*)d_in[4];
  const float* b1  = (const float*)d_in[5];
  const float* W2  = (const float*)d_in[6];
  const float* b2  = (const float*)d_in[7];
  const float* g1  = (const float*)d_in[8];
  const float* be1 = (const float*)d_in[9];
  const float* g2  = (const float*)d_in[10];
  const float* be2 = (const float*)d_in[11];
  float* out = (float*)d_out;

  constexpr long BSD = 8L * 2048 * 1024;
  constexpr long BSS = 8L * 2048 * 2048;
  constexpr long DD  = 1024L * 1024;
  constexpr long HD  = 2048L * 1024;

  // Scratch: qb | kb | vTb | sP | r1  = 234,881,024 bytes total.
  ushort_t* qb  = (ushort_t*)d_ws;
  ushort_t* kb  = qb + BSD;
  ushort_t* vTb = kb + BSD;
  ushort_t* sP  = vTb + BSD;
  float*    r1  = (float*)(sP + BSS);

  ushort_t* xb    = sP;              // dead before scores written
  ushort_t* Wqkvb = (ushort_t*)r1;   // dead before PV writes r1
  ushort_t* W1b   = kb;              // converted after scores GEMM
  ushort_t* W2b   = kb + HD;
  ushort_t* hb    = qb;
  float*    h     = out;             // d_out dead until LN2 rewrites it

  dim3 blk(256), gblk(512);
  const long SD = 2048L * 1024, SS = 2048L * 2048, DS = 1024L * 2048;

  // 0: conversions
  cvt_f32_bf16<<<dim3(8192), blk, 0, stream>>>(x, xb, BSD);
  cvt_f32_bf16<<<dim3(512), blk, 0, stream>>>(Wq, Wqkvb, DD);
  cvt_f32_bf16<<<dim3(512), blk, 0, stream>>>(Wk, Wqkvb + DD, DD);
  cvt_f32_bf16<<<dim3(512), blk, 0, stream>>>(Wv, Wqkvb + 2 * DD, DD);
  // 1: fused QKV projection (M=16384, N=3072, K=1024)
  gemm_bt<EP_QKV><<<dim3(64, 12, 1), gblk, 0, stream>>>(
      xb, Wqkvb, qb, 3072, 1024, 0, 0, 0, 0, nullptr, nullptr, 1.f);
  // 2: scores = q@k^T / 32 (per batch: M=N=2048, K=1024)
  gemm_bt<EP_BF16><<<dim3(8, 8, 8), gblk, 0, stream>>>(
      qb, kb, sP, 2048, 1024, SD, SD, SS, 0, nullptr, nullptr, 0.03125f);
  // 2b: FFN weights into kb region (kb dead now)
  cvt_f32_bf16<<<dim3(1024), blk, 0, stream>>>(W1, W1b, HD);
  cvt_f32_bf16<<<dim3(1024), blk, 0, stream>>>(W2, W2b, HD);
  // 3: softmax
  softmax_inplace<<<dim3(16384), blk, 0, stream>>>(sP);
  // 4: attn_out + x (per batch: M=2048, N=1024, K=2048)
  gemm_bt<EP_PV><<<dim3(8, 4, 8), gblk, 0, stream>>>(
      sP, vTb, r1, 1024, 2048, SS, DS, SD, SD, nullptr, x, 1.f);
  // 5: LN1 -> h (fp32, in d_out) + hb (bf16, aliases qb)
  ln_row<0><<<dim3(16384), blk, 0, stream>>>(r1, g1, be1, h, hb);
  // 6: ff1 = relu(hb@W1^T + b1) (M=16384, N=2048, K=1024)
  gemm_bt<EP_FF1><<<dim3(64, 8, 1), gblk, 0, stream>>>(
      hb, W1b, sP, 2048, 1024, 0, 0, 0, 0, b1, nullptr, 1.f);
  // 7: res2 = ff1@W2^T + b2 + h (M=16384, N=1024, K=2048)
  gemm_bt<EP_FF2><<<dim3(64, 4, 1), gblk, 0, stream>>>(
      sP, W2b, r1, 1024, 2048, 0, 0, 0, 0, b2, h, 1.f);
  // 8: LN2 -> out (overwrites h)
  ln_row<1><<<dim3(16384), blk, 0, stream>>>(r1, g2, be2, out, nullptr);
}

// Round 6
// 548.005 us; speedup vs baseline: 1.7647x; 1.0465x over previous
//
#include <hip/hip_runtime.h>
#include <hip/hip_bf16.h>

// ---------------------------------------------------------------------------
// MiniTransformer: B=8,S=2048,D=1024,H=2048, fp32 in/out, bf16 MFMA inside.
// GEMM: 256x256 tile, BK=32, 8 waves (2Mx4N), 4-deep LDS pipeline (128KB),
// 8-phase-style schedule: per K-tile 2 phases, each {ds_read subtile ||
// 2 global_load_lds -> lgkmcnt(0) -> 16 MFMA (setprio)} with counted
// s_waitcnt vmcnt(8) at tile boundaries (3-K-tile prefetch lead, never
// drains to 0 in steady state). Conflict-free involutive chunk-XOR LDS
// layout (verified 0 conflicts in R5): K-tile = [128 ldsrows][128B], 2 tile
// rows per ldsrow, slot = ((r&1)*4 + kchunk) ^ (ldsrow&7).
// Pipeline:
//   0.  cvt: xb = bf16(x); Wqkv_b = bf16(concat(Wq,Wk,Wv)) [3072,1024]
//   1.  gemm EP_QKV:  [q|k|vT] = xb @ Wqkv^T  (one GEMM, N=3072)
//   2.  gemm EP_BF16: scores = q@k^T /32 (per batch)
//   2b. cvt: W1b, W2b (into kb region, dead after step 2)
//   3.  softmax in place (scores -> P)
//   4.  gemm EP_PV:   r1 = P@V + x (fp32)
//   5.  LN1 -> h (fp32, in d_out) + hb (bf16, aliases qb)
//   6.  gemm EP_FF1:  ff1 = relu(hb@W1^T + b1) -> sP
//   7.  gemm EP_FF2:  r1 = ff1@W2^T + b2 + h
//   8.  LN2 -> d_out
// Scratch (234,881,024 B): qb|kb|vTb|sP|r1 as before.
// ---------------------------------------------------------------------------

typedef __attribute__((ext_vector_type(4))) float  f32x4;
typedef __attribute__((ext_vector_type(8))) short  short8;
typedef __attribute__((ext_vector_type(4))) short  short4v;
typedef __attribute__((ext_vector_type(8))) __bf16 bf16x8;
typedef unsigned short ushort_t;

static __device__ __forceinline__ unsigned short f2bf(float f) {
  unsigned u = __builtin_bit_cast(unsigned, f);
  u += 0x7fffu + ((u >> 16) & 1u);  // RNE
  return (unsigned short)(u >> 16);
}
static __device__ __forceinline__ float bf2f(unsigned short u) {
  return __builtin_bit_cast(float, (unsigned)u << 16);
}

#define GLDS16(g, l)                                                        \
  __builtin_amdgcn_global_load_lds(                                         \
      (const __attribute__((address_space(1))) void*)(g),                   \
      (__attribute__((address_space(3))) void*)(l), 16, 0, 0)

// ---------------------------------------------------------------------------
// fp32 -> bf16 conversion, 8 elems/thread.
// ---------------------------------------------------------------------------
__global__ __launch_bounds__(256) void cvt_f32_bf16(
    const float* __restrict__ in, ushort_t* __restrict__ out, long n) {
  long i = ((long)blockIdx.x * 256 + threadIdx.x) * 8;
  if (i >= n) return;
  f32x4 a = *(const f32x4*)(in + i);
  f32x4 b = *(const f32x4*)(in + i + 4);
  short8 t;
  t[0] = (short)f2bf(a.x); t[1] = (short)f2bf(a.y);
  t[2] = (short)f2bf(a.z); t[3] = (short)f2bf(a.w);
  t[4] = (short)f2bf(b.x); t[5] = (short)f2bf(b.y);
  t[6] = (short)f2bf(b.z); t[7] = (short)f2bf(b.w);
  *(short8*)(out + i) = t;
}

// ---------------------------------------------------------------------------
// GEMM: C[M,N] = A[M,K] @ B[N,K]^T, bf16 operands, fp32 accum.
// ---------------------------------------------------------------------------
enum { EP_QKV = 0, EP_BF16 = 1, EP_PV = 2, EP_FF1 = 3, EP_FF2 = 4 };

constexpr long BSDc = 8L * 2048 * 1024;

template <int EPI>
__global__ __launch_bounds__(512, 2) void gemm_bt(
    const ushort_t* __restrict__ A, const ushort_t* __restrict__ B,
    void* __restrict__ C, int N, int K, long sA, long sB, long sC, long sRes,
    const float* __restrict__ bias, const float* __restrict__ res,
    float scale) {
  // 4-deep pipeline: one K-tile (256 rows x 32 k = 16KB) per operand per buf.
  __shared__ __align__(16) ushort_t As[4][8192];
  __shared__ __align__(16) ushort_t Bs[4][8192];
  const int tid  = threadIdx.x;
  const int lane = tid & 63;
  const int w    = tid >> 6;        // 0..7
  const int wm   = w >> 2;          // 0..1 : wave row (128 rows each)
  const int wn   = w & 3;           // 0..3 : wave col (64 cols each)
  const int l15  = lane & 15;
  const int hi   = lane >> 4;       // 0..3 : 8-elem k-chunk within BK=32
  const long bz  = blockIdx.z;
  const long m0  = (long)blockIdx.x * 256;
  const long n0  = (long)blockIdx.y * 256;
  const ushort_t* Ab = A + bz * sA;
  const ushort_t* Bb = B + bz * sB;

  // --- staging source offsets (inverse of the read-side XOR swizzle) ---
  // phys chunk P = q*512 + tid (written linearly by GLDS, 16B each):
  // ldsrow = P>>3, slot = (P&7)^(ldsrow&7), r = 2*ldsrow + (slot>>2),
  // kchunk = slot&3 ; global elem = (row0 + r)*K + u*32 + kchunk*8.
  long aoff[2], boff[2];
#pragma unroll
  for (int q = 0; q < 2; ++q) {
    int P  = q * 512 + tid;
    int lr = P >> 3;
    int sl = (P & 7) ^ (lr & 7);
    int r  = 2 * lr + (sl >> 2);
    int kc = sl & 3;
    aoff[q] = (m0 + r) * (long)K + kc * 8;
    boff[q] = (n0 + r) * (long)K + kc * 8;
  }

  // phase A stages the A K-tile (2 loads), phase B the B K-tile (2 loads).
#define STAGEA(u)                                                           \
  {                                                                         \
    const long kk0 = (long)(u) * 32;                                        \
    const int dbf  = (u) & 3;                                               \
    GLDS16(Ab + aoff[0] + kk0, &As[dbf][w * 512]);                          \
    GLDS16(Ab + aoff[1] + kk0, &As[dbf][4096 + w * 512]);                   \
  }
#define STAGEB(u)                                                           \
  {                                                                         \
    const long kk0 = (long)(u) * 32;                                        \
    const int dbf  = (u) & 3;                                               \
    GLDS16(Bb + boff[0] + kk0, &Bs[dbf][w * 512]);                          \
    GLDS16(Bb + boff[1] + kk0, &Bs[dbf][4096 + w * 512]);                   \
  }

  // --- read-side swizzled byte offsets (constant per lane) ---
  // frag row r: ldsrow = r>>1, slot = ((r&1)*4 + hi) ^ (ldsrow&7);
  // (ldsrow&7) == (l15>>1) for all frags since row strides are mult. of 16.
  const int slotR = (((l15 & 1) << 2) | hi) ^ (l15 >> 1);
  const int abase = wm * 8192 + (l15 >> 1) * 128 + slotR * 16;
  const int bbase = wn * 4096 + (l15 >> 1) * 128 + slotR * 16;

  f32x4 acc[8][4] = {};
  const int NT = K >> 5;

  // Prologue: prime 3 K-tiles (12 loads/thread); retire tile 0 (keep 8).
  STAGEA(0) STAGEB(0) STAGEA(1) STAGEB(1) STAGEA(2) STAGEB(2)
  asm volatile("s_waitcnt vmcnt(8)" ::: "memory");
  __builtin_amdgcn_sched_barrier(0);
  __builtin_amdgcn_s_barrier();

  for (int u = 0; u < NT; ++u) {
    const int bf = u & 3;
    const char* Ad = (const char*)&As[bf][0];
    const char* Bd = (const char*)&Bs[bf][0];
    short8 af[8], bq[4];
    // ---- phase A: frags for C-rows 0..63 of this wave + all B frags ----
#pragma unroll
    for (int i = 0; i < 4; ++i)
      af[i] = *(const short8*)(Ad + abase + i * 1024);
#pragma unroll
    for (int j = 0; j < 4; ++j)
      bq[j] = *(const short8*)(Bd + bbase + j * 1024);
    if (u + 3 < NT) STAGEA(u + 3)
    asm volatile("s_waitcnt lgkmcnt(0)" ::: "memory");
    __builtin_amdgcn_sched_barrier(0);
    __builtin_amdgcn_s_setprio(1);
#pragma unroll
    for (int i = 0; i < 4; ++i)
#pragma unroll
      for (int j = 0; j < 4; ++j)
        acc[i][j] = __builtin_amdgcn_mfma_f32_16x16x32_bf16(
            __builtin_bit_cast(bf16x8, af[i]), __builtin_bit_cast(bf16x8, bq[j]),
            acc[i][j], 0, 0, 0);
    __builtin_amdgcn_s_setprio(0);
    __builtin_amdgcn_sched_barrier(0);
    __builtin_amdgcn_s_barrier();
    // ---- phase B: frags for C-rows 64..127 ----
#pragma unroll
    for (int i = 4; i < 8; ++i)
      af[i] = *(const short8*)(Ad + abase + i * 1024);
    if (u + 3 < NT) STAGEB(u + 3)
    asm volatile("s_waitcnt lgkmcnt(0)" ::: "memory");
    __builtin_amdgcn_sched_barrier(0);
    __builtin_amdgcn_s_setprio(1);
#pragma unroll
    for (int i = 4; i < 8; ++i)
#pragma unroll
      for (int j = 0; j < 4; ++j)
        acc[i][j] = __builtin_amdgcn_mfma_f32_16x16x32_bf16(
            __builtin_bit_cast(bf16x8, af[i]), __builtin_bit_cast(bf16x8, bq[j]),
            acc[i][j], 0, 0, 0);
    __builtin_amdgcn_s_setprio(0);
    __builtin_amdgcn_sched_barrier(0);
    // ---- tile boundary: buf u+1 must be resident; keep later tiles flying
    if (u + 1 < NT) {
      if (u + 3 < NT) {        // stage(u+3) issued this tile; keep (u+2,u+3)
        asm volatile("s_waitcnt vmcnt(8)" ::: "memory");
      } else if (u + 3 == NT) {  // last stage was u+2; keep it in flight
        asm volatile("s_waitcnt vmcnt(4)" ::: "memory");
      } else {                   // nothing newer than u+1 outstanding
        asm volatile("s_waitcnt vmcnt(0)" ::: "memory");
      }
      __builtin_amdgcn_sched_barrier(0);
      __builtin_amdgcn_s_barrier();
    }
  }
#undef STAGEA
#undef STAGEB

  // Epilogue. C/D layout: col = lane&15, row = (lane>>4)*4 + reg.
  const int rb0 = hi << 2;
  const int cl  = l15;
#pragma unroll
  for (int i = 0; i < 8; ++i) {
#pragma unroll
    for (int j = 0; j < 4; ++j) {
      long gmb = m0 + wm * 128 + i * 16 + rb0;
      long gc  = n0 + wn * 64 + j * 16 + cl;
      if constexpr (EPI == EP_QKV) {
        long which = gc >> 10;  // 0=q, 1=k, 2=v (uniform per block)
        long col   = gc & 1023;
        if (which == 2) {
          long bb = gmb >> 11, s = gmb & 2047;
          short4v pk;
#pragma unroll
          for (int r = 0; r < 4; ++r) pk[r] = (short)f2bf(acc[i][j][r]);
          *(short4v*)((ushort_t*)C + 2 * BSDc + ((bb << 10) + col) * 2048 + s) =
              pk;
        } else {
#pragma unroll
          for (int r = 0; r < 4; ++r)
            ((ushort_t*)C)[which * BSDc + (gmb + r) * 1024 + col] =
                f2bf(acc[i][j][r]);
        }
      } else {
#pragma unroll
        for (int r = 0; r < 4; ++r) {
          long gm = gmb + r;
          float v = acc[i][j][r] * scale;
          if constexpr (EPI == EP_BF16) {
            ((ushort_t*)C)[bz * sC + gm * N + gc] = f2bf(v);
          } else if constexpr (EPI == EP_PV) {
            v += res[bz * sRes + gm * N + gc];
            ((float*)C)[bz * sC + gm * N + gc] = v;
          } else if constexpr (EPI == EP_FF1) {
            v += bias[gc];
            v = v > 0.f ? v : 0.f;
            ((ushort_t*)C)[gm * N + gc] = f2bf(v);
          } else {  // EP_FF2
            v += bias[gc] + res[gm * N + gc];
            ((float*)C)[gm * N + gc] = v;
          }
        }
      }
    }
  }
}

// ---------------------------------------------------------------------------
// Row softmax, in place on bf16 (B*S rows of 2048). 256 thr, 8 el/thread.
// ---------------------------------------------------------------------------
__global__ __launch_bounds__(256) void softmax_inplace(
    ushort_t* __restrict__ P) {
  __shared__ float rmax[4], rsum[4];
  const int tid   = threadIdx.x;
  const long base = (long)blockIdx.x * 2048;
  short8 sv = *(const short8*)(P + base + tid * 8);
  float v[8];
#pragma unroll
  for (int j = 0; j < 8; ++j) v[j] = bf2f((unsigned short)sv[j]);
  float mx = v[0];
#pragma unroll
  for (int j = 1; j < 8; ++j) mx = fmaxf(mx, v[j]);
#pragma unroll
  for (int off = 32; off; off >>= 1) mx = fmaxf(mx, __shfl_down(mx, off, 64));
  if ((tid & 63) == 0) rmax[tid >> 6] = mx;
  __syncthreads();
  mx = fmaxf(fmaxf(rmax[0], rmax[1]), fmaxf(rmax[2], rmax[3]));
  float s = 0.f;
#pragma unroll
  for (int j = 0; j < 8; ++j) {
    v[j] = __expf(v[j] - mx);
    s += v[j];
  }
#pragma unroll
  for (int off = 32; off; off >>= 1) s += __shfl_down(s, off, 64);
  if ((tid & 63) == 0) rsum[tid >> 6] = s;
  __syncthreads();
  s = (rsum[0] + rsum[1]) + (rsum[2] + rsum[3]);
  float inv = 1.f / s;
  short8 o;
#pragma unroll
  for (int j = 0; j < 8; ++j) o[j] = (short)f2bf(v[j] * inv);
  *(short8*)(P + base + tid * 8) = o;
}

// ---------------------------------------------------------------------------
// Row LayerNorm over D=1024. MODE 0: write fp32 + bf16; MODE 1: fp32 only.
// ---------------------------------------------------------------------------
template <int MODE>
__global__ __launch_bounds__(256) void ln_row(const float* __restrict__ X,
                                              const float* __restrict__ g,
                                              const float* __restrict__ be,
                                              float* __restrict__ Yf,
                                              ushort_t* __restrict__ Yb) {
  __shared__ float rs[4], rq[4];
  const int tid   = threadIdx.x;
  const long base = (long)blockIdx.x << 10;
  f32x4 v = *(const f32x4*)(X + base + tid * 4);
  float s = v.x + v.y + v.z + v.w;
  float q = v.x * v.x + v.y * v.y + v.z * v.z + v.w * v.w;
#pragma unroll
  for (int off = 32; off; off >>= 1) {
    s += __shfl_down(s, off, 64);
    q += __shfl_down(q, off, 64);
  }
  if ((tid & 63) == 0) {
    rs[tid >> 6] = s;
    rq[tid >> 6] = q;
  }
  __syncthreads();
  s = (rs[0] + rs[1]) + (rs[2] + rs[3]);
  q = (rq[0] + rq[1]) + (rq[2] + rq[3]);
  float mu   = s * (1.f / 1024.f);
  float var  = q * (1.f / 1024.f) - mu * mu;
  float rstd = rsqrtf(var + 1e-5f);
  int c    = tid * 4;
  f32x4 gg = *(const f32x4*)(g + c);
  f32x4 bb = *(const f32x4*)(be + c);
  f32x4 y;
  y.x = (v.x - mu) * rstd * gg.x + bb.x;
  y.y = (v.y - mu) * rstd * gg.y + bb.y;
  y.z = (v.z - mu) * rstd * gg.z + bb.z;
  y.w = (v.w - mu) * rstd * gg.w + bb.w;
  *(f32x4*)(Yf + base + c) = y;
  if constexpr (MODE == 0) {
    short4v ob;
    ob[0] = (short)f2bf(y.x);
    ob[1] = (short)f2bf(y.y);
    ob[2] = (short)f2bf(y.z);
    ob[3] = (short)f2bf(y.w);
    *(short4v*)(Yb + base + c) = ob;
  }
}

// ---------------------------------------------------------------------------
extern "C" void kernel_launch(void* const* d_in, const int* in_sizes, int n_in,
                              void* d_out, int out_size, void* d_ws,
                              size_t ws_size, hipStream_t stream) {
  const float* x   = (const float*)d_in[0];
  const float* Wq  = (const float*)d_in[1];
  const float* Wk  = (const float*)d_in[2];
  const float* Wv  = (const float*)d_in[3];
  const float* W1  = (const float*)d_in[4];
  const float* b1  = (const float*)d_in[5];
  const float* W2  = (const float*)d_in[6];
  const float* b2  = (const float*)d_in[7];
  const float* g1  = (const float*)d_in[8];
  const float* be1 = (const float*)d_in[9];
  const float* g2  = (const float*)d_in[10];
  const float* be2 = (const float*)d_in[11];
  float* out = (float*)d_out;

  constexpr long BSD = 8L * 2048 * 1024;
  constexpr long BSS = 8L * 2048 * 2048;
  constexpr long DD  = 1024L * 1024;
  constexpr long HD  = 2048L * 1024;

  // Scratch: qb | kb | vTb | sP | r1  = 234,881,024 bytes total.
  ushort_t* qb  = (ushort_t*)d_ws;
  ushort_t* kb  = qb + BSD;
  ushort_t* vTb = kb + BSD;
  ushort_t* sP  = vTb + BSD;
  float*    r1  = (float*)(sP + BSS);

  ushort_t* xb    = sP;              // dead before scores written
  ushort_t* Wqkvb = (ushort_t*)r1;   // dead before PV writes r1
  ushort_t* W1b   = kb;              // converted after scores GEMM
  ushort_t* W2b   = kb + HD;
  ushort_t* hb    = qb;
  float*    h     = out;             // d_out dead until LN2 rewrites it

  dim3 blk(256), gblk(512);
  const long SD = 2048L * 1024, SS = 2048L * 2048, DS = 1024L * 2048;

  // 0: conversions
  cvt_f32_bf16<<<dim3(8192), blk, 0, stream>>>(x, xb, BSD);
  cvt_f32_bf16<<<dim3(512), blk, 0, stream>>>(Wq, Wqkvb, DD);
  cvt_f32_bf16<<<dim3(512), blk, 0, stream>>>(Wk, Wqkvb + DD, DD);
  cvt_f32_bf16<<<dim3(512), blk, 0, stream>>>(Wv, Wqkvb + 2 * DD, DD);
  // 1: fused QKV projection (M=16384, N=3072, K=1024)
  gemm_bt<EP_QKV><<<dim3(64, 12, 1), gblk, 0, stream>>>(
      xb, Wqkvb, qb, 3072, 1024, 0, 0, 0, 0, nullptr, nullptr, 1.f);
  // 2: scores = q@k^T / 32 (per batch: M=N=2048, K=1024)
  gemm_bt<EP_BF16><<<dim3(8, 8, 8), gblk, 0, stream>>>(
      qb, kb, sP, 2048, 1024, SD, SD, SS, 0, nullptr, nullptr, 0.03125f);
  // 2b: FFN weights into kb region (kb dead now)
  cvt_f32_bf16<<<dim3(1024), blk, 0, stream>>>(W1, W1b, HD);
  cvt_f32_bf16<<<dim3(1024), blk, 0, stream>>>(W2, W2b, HD);
  // 3: softmax
  softmax_inplace<<<dim3(16384), blk, 0, stream>>>(sP);
  // 4: attn_out + x (per batch: M=2048, N=1024, K=2048)
  gemm_bt<EP_PV><<<dim3(8, 4, 8), gblk, 0, stream>>>(
      sP, vTb, r1, 1024, 2048, SS, DS, SD, SD, nullptr, x, 1.f);
  // 5: LN1 -> h (fp32, in d_out) + hb (bf16, aliases qb)
  ln_row<0><<<dim3(16384), blk, 0, stream>>>(r1, g1, be1, h, hb);
  // 6: ff1 = relu(hb@W1^T + b1) (M=16384, N=2048, K=1024)
  gemm_bt<EP_FF1><<<dim3(64, 8, 1), gblk, 0, stream>>>(
      hb, W1b, sP, 2048, 1024, 0, 0, 0, 0, b1, nullptr, 1.f);
  // 7: res2 = ff1@W2^T + b2 + h (M=16384, N=1024, K=2048)
  gemm_bt<EP_FF2><<<dim3(64, 4, 1), gblk, 0, stream>>>(
      sP, W2b, r1, 1024, 2048, 0, 0, 0, 0, b2, h, 1.f);
  // 8: LN2 -> out (overwrites h)
  ln_row<1><<<dim3(16384), blk, 0, stream>>>(r1, g2, be2, out, nullptr);
}